// Round 1
// baseline (2171.290 us; speedup 1.0000x reference)
//
#include <hip/hip_runtime.h>
#include <hip/hip_bf16.h>

#define NN 100000
#define NE 3200000
#define FIN 256
#define F1 16
#define F2 32
#define CO 64
#define NC 1000

// workspace layout (float offsets)
#define OFF_DINV 0
#define OFF_H1   100352
#define OFF_OUT1 1700352
#define OFF_H2   3300352
#define OFF_OUT2 100352   /* aliases h1+out1 (both dead when written) */
#define OFF_POOL 6500352

__device__ __forceinline__ unsigned enc_f(float f) {
    unsigned u = __float_as_uint(f);
    return (u & 0x80000000u) ? ~u : (u | 0x80000000u);
}
__device__ __forceinline__ float dec_f(unsigned u) {
    return (u & 0x80000000u) ? __uint_as_float(u & 0x7fffffffu) : __uint_as_float(~u);
}

// ---------- K0: in-degree count (int atomics into dinv buffer) ----------
__global__ void k_deg(const int* __restrict__ ei, unsigned* __restrict__ deg) {
    int e = blockIdx.x * 256 + threadIdx.x;
    if (e < NE) atomicAdd(&deg[ei[NE + e]], 1u);
}

// ---------- K1: dinv = rsqrt(deg + 1) in place ----------
__global__ void k_dinv(float* __restrict__ dinv) {
    int i = blockIdx.x * 256 + threadIdx.x;
    if (i < NN) {
        unsigned c = ((const unsigned*)dinv)[i];
        dinv[i] = rsqrtf((float)(c + 1u));
    }
}

// ---------- K2: h1 = X @ W1  (100000x256 @ 256x16) ----------
__global__ __launch_bounds__(256) void k_gemm1(const float* __restrict__ X,
                                               const float* __restrict__ W1,
                                               float* __restrict__ h1) {
    __shared__ float Xs[32][257];
    __shared__ float4 Ws[1024];   // W1 as float4: [256 k][4 colgroups]
    int tid = threadIdx.x;
    const float4* W14 = (const float4*)W1;
    for (int i = tid; i < 1024; i += 256) Ws[i] = W14[i];

    int rowbase = blockIdx.x * 256;
    int q  = tid >> 2;      // 0..63 (row within quarter)
    int cg = tid & 3;       // col group (4 floats each)
    float4 acc[4] = {};

    for (int kt = 0; kt < 8; ++kt) {
        __syncthreads();
        // stage 256 rows x 32 k
        #pragma unroll
        for (int it = 0; it < 8; ++it) {
            int fl = tid + it * 256;       // float4 index 0..2047
            int rl = fl >> 3;              // 0..255
            int c4 = (fl & 7) << 2;        // 0..28
            int gr = rowbase + rl;
            float4 v = make_float4(0.f, 0.f, 0.f, 0.f);
            if (gr < NN) v = *(const float4*)(X + (size_t)gr * FIN + kt * 32 + c4);
            Xs[c4 + 0][rl] = v.x;
            Xs[c4 + 1][rl] = v.y;
            Xs[c4 + 2][rl] = v.z;
            Xs[c4 + 3][rl] = v.w;
        }
        __syncthreads();
        #pragma unroll
        for (int kk = 0; kk < 32; ++kk) {
            float4 w4 = Ws[(kt * 32 + kk) * 4 + cg];
            #pragma unroll
            for (int m = 0; m < 4; ++m) {
                float xv = Xs[kk][q + 64 * m];
                acc[m].x += xv * w4.x;
                acc[m].y += xv * w4.y;
                acc[m].z += xv * w4.z;
                acc[m].w += xv * w4.w;
            }
        }
    }
    #pragma unroll
    for (int m = 0; m < 4; ++m) {
        int r = rowbase + q + 64 * m;
        if (r < NN) *(float4*)(h1 + (size_t)r * F1 + cg * 4) = acc[m];
    }
}

// ---------- K3a: out1 = h1 * dinv^2 (self-loop term) ----------
__global__ void k_loop1(const float* __restrict__ h1, const float* __restrict__ dinv,
                        float* __restrict__ out1) {
    int i = blockIdx.x * 256 + threadIdx.x;
    if (i < NN * F1) {
        int n = i >> 4;
        float d = dinv[n];
        out1[i] = h1[i] * d * d;
    }
}

// ---------- K3b: edge scatter layer 1 ----------
__global__ void k_scat1(const int* __restrict__ ei, const float* __restrict__ dinv,
                        const float* __restrict__ h1, float* __restrict__ out1) {
    int t = blockIdx.x * 256 + threadIdx.x;
    int e = t >> 2, fq = (t & 3) << 2;
    int src = ei[e], dst = ei[NE + e];
    float nrm = dinv[src] * dinv[dst];
    float4 hv = *(const float4*)(h1 + (size_t)src * F1 + fq);
    float* o = out1 + (size_t)dst * F1 + fq;
    unsafeAtomicAdd(o + 0, hv.x * nrm);
    unsafeAtomicAdd(o + 1, hv.y * nrm);
    unsafeAtomicAdd(o + 2, hv.z * nrm);
    unsafeAtomicAdd(o + 3, hv.w * nrm);
}

// ---------- K4: h2 = relu(out1 + b1) @ W2  (16 -> 32) ----------
__global__ __launch_bounds__(256) void k_gemm2(const float* __restrict__ out1,
                                               const float* __restrict__ b1,
                                               const float* __restrict__ W2,
                                               float* __restrict__ h2) {
    __shared__ float4 Ws[128];  // W2 [16][8] float4
    __shared__ float B1[16];
    int tid = threadIdx.x;
    if (tid < 128) Ws[tid] = ((const float4*)W2)[tid];
    if (tid < 16) B1[tid] = b1[tid];
    __syncthreads();
    int n = blockIdx.x * 256 + tid;
    if (n >= NN) return;
    float r[16];
    #pragma unroll
    for (int f4 = 0; f4 < 4; ++f4) {
        float4 v = *(const float4*)(out1 + (size_t)n * F1 + f4 * 4);
        r[f4 * 4 + 0] = fmaxf(v.x + B1[f4 * 4 + 0], 0.f);
        r[f4 * 4 + 1] = fmaxf(v.y + B1[f4 * 4 + 1], 0.f);
        r[f4 * 4 + 2] = fmaxf(v.z + B1[f4 * 4 + 2], 0.f);
        r[f4 * 4 + 3] = fmaxf(v.w + B1[f4 * 4 + 3], 0.f);
    }
    #pragma unroll
    for (int cg = 0; cg < 8; ++cg) {
        float4 a = make_float4(0.f, 0.f, 0.f, 0.f);
        #pragma unroll
        for (int f = 0; f < 16; ++f) {
            float4 w = Ws[f * 8 + cg];
            a.x += r[f] * w.x;
            a.y += r[f] * w.y;
            a.z += r[f] * w.z;
            a.w += r[f] * w.w;
        }
        *(float4*)(h2 + (size_t)n * F2 + cg * 4) = a;
    }
}

// ---------- K5a: out2 = h2 * dinv^2 + b2 ----------
__global__ void k_loop2(const float* __restrict__ h2, const float* __restrict__ dinv,
                        const float* __restrict__ b2, float* __restrict__ out2) {
    int i = blockIdx.x * 256 + threadIdx.x;
    if (i < NN * F2) {
        int n = i >> 5, c = i & 31;
        float d = dinv[n];
        out2[i] = h2[i] * d * d + b2[c];
    }
}

// ---------- K5b: edge scatter layer 2 ----------
__global__ void k_scat2(const int* __restrict__ ei, const float* __restrict__ dinv,
                        const float* __restrict__ h2, float* __restrict__ out2) {
    int t = blockIdx.x * 256 + threadIdx.x;
    int e = t >> 3, cq = (t & 7) << 2;
    int src = ei[e], dst = ei[NE + e];
    float nrm = dinv[src] * dinv[dst];
    float4 hv = *(const float4*)(h2 + (size_t)src * F2 + cq);
    float* o = out2 + (size_t)dst * F2 + cq;
    unsafeAtomicAdd(o + 0, hv.x * nrm);
    unsafeAtomicAdd(o + 1, hv.y * nrm);
    unsafeAtomicAdd(o + 2, hv.z * nrm);
    unsafeAtomicAdd(o + 3, hv.w * nrm);
}

// ---------- K6: conv1d(32->64, k=3, pad 1) + global max (bias deferred) ----------
#define NPB 256
__global__ __launch_bounds__(256) void k_conv(const float* __restrict__ h2f,
                                              const float* __restrict__ cw,
                                              unsigned* __restrict__ pool) {
    __shared__ float Hs[NPB + 2][33];
    __shared__ float Wt[3 * 32 * 64];   // [k][ci][o]
    __shared__ float4 Ms[4][16];
    int tid = threadIdx.x;
    int base = blockIdx.x * NPB;
    // weights: cw flat [o][ci][1][3] -> Wt[k][ci][o]
    for (int idx = tid; idx < 6144; idx += 256) {
        int o = idx / 96, r = idx % 96, ci = r / 3, k = r % 3;
        Wt[(k * 32 + ci) * 64 + o] = cw[idx];
    }
    // stage rows base-1 .. base+256
    for (int idx = tid; idx < (NPB + 2) * 8; idx += 256) {
        int j = idx >> 3, c4 = (idx & 7) << 2;
        int g = base + j - 1;
        float4 v = make_float4(0.f, 0.f, 0.f, 0.f);
        if (g >= 0 && g < NN) v = *(const float4*)(h2f + (size_t)g * F2 + c4);
        Hs[j][c4 + 0] = v.x;
        Hs[j][c4 + 1] = v.y;
        Hs[j][c4 + 2] = v.z;
        Hs[j][c4 + 3] = v.w;
    }
    __syncthreads();

    int o4 = (tid & 15) * 4;
    int ng = tid >> 4;          // 0..15, 16 nodes each
    float4 acc[16] = {};
    for (int ci = 0; ci < 32; ++ci) {
        float h[18];
        #pragma unroll
        for (int j = 0; j < 18; ++j) h[j] = Hs[ng * 16 + j][ci];
        #pragma unroll
        for (int k = 0; k < 3; ++k) {
            float4 w = *(const float4*)&Wt[(k * 32 + ci) * 64 + o4];
            #pragma unroll
            for (int i = 0; i < 16; ++i) {
                float hv = h[i + k];
                acc[i].x += hv * w.x;
                acc[i].y += hv * w.y;
                acc[i].z += hv * w.z;
                acc[i].w += hv * w.w;
            }
        }
    }
    const float NI = -3.0e38f;
    float4 m4 = make_float4(NI, NI, NI, NI);
    #pragma unroll
    for (int i = 0; i < 16; ++i) {
        if (base + ng * 16 + i < NN) {
            m4.x = fmaxf(m4.x, acc[i].x);
            m4.y = fmaxf(m4.y, acc[i].y);
            m4.z = fmaxf(m4.z, acc[i].z);
            m4.w = fmaxf(m4.w, acc[i].w);
        }
    }
    // reduce across the 4 node-groups within each wave (tid bits 4,5)
    #pragma unroll
    for (int off = 16; off <= 32; off <<= 1) {
        m4.x = fmaxf(m4.x, __shfl_xor(m4.x, off));
        m4.y = fmaxf(m4.y, __shfl_xor(m4.y, off));
        m4.z = fmaxf(m4.z, __shfl_xor(m4.z, off));
        m4.w = fmaxf(m4.w, __shfl_xor(m4.w, off));
    }
    int lane = tid & 63, wv = tid >> 6;
    if (lane < 16) Ms[wv][lane] = m4;
    __syncthreads();
    if (tid < 16) {
        float4 a = Ms[0][tid], b = Ms[1][tid], c = Ms[2][tid], d = Ms[3][tid];
        a.x = fmaxf(fmaxf(a.x, b.x), fmaxf(c.x, d.x));
        a.y = fmaxf(fmaxf(a.y, b.y), fmaxf(c.y, d.y));
        a.z = fmaxf(fmaxf(a.z, b.z), fmaxf(c.z, d.z));
        a.w = fmaxf(fmaxf(a.w, b.w), fmaxf(c.w, d.w));
        int o = tid * 4;
        atomicMax(&pool[o + 0], enc_f(a.x));
        atomicMax(&pool[o + 1], enc_f(a.y));
        atomicMax(&pool[o + 2], enc_f(a.z));
        atomicMax(&pool[o + 3], enc_f(a.w));
    }
}

// ---------- K7: out = (pooled + conv_b) @ fc_w^T + fc_b ----------
__global__ void k_fc(const unsigned* __restrict__ pool, const float* __restrict__ cb,
                     const float* __restrict__ fw, const float* __restrict__ fb,
                     float* __restrict__ out) {
    __shared__ float P[64];
    int tid = threadIdx.x;
    if (tid < 64) P[tid] = dec_f(pool[tid]) + cb[tid];
    __syncthreads();
    int j = blockIdx.x * 256 + tid;
    if (j >= NC) return;
    float s = fb[j];
    const float4* wr = (const float4*)(fw + (size_t)j * CO);
    #pragma unroll
    for (int c = 0; c < 16; ++c) {
        float4 w = wr[c];
        s += P[c * 4 + 0] * w.x + P[c * 4 + 1] * w.y +
             P[c * 4 + 2] * w.z + P[c * 4 + 3] * w.w;
    }
    out[j] = s;
}

extern "C" void kernel_launch(void* const* d_in, const int* in_sizes, int n_in,
                              void* d_out, int out_size, void* d_ws, size_t ws_size,
                              hipStream_t stream) {
    const float* x  = (const float*)d_in[0];
    const int*   ei = (const int*)d_in[1];
    const float* W1 = (const float*)d_in[2];
    const float* b1 = (const float*)d_in[3];
    const float* W2 = (const float*)d_in[4];
    const float* b2 = (const float*)d_in[5];
    const float* cw = (const float*)d_in[6];
    const float* cb = (const float*)d_in[7];
    const float* fw = (const float*)d_in[8];
    const float* fb = (const float*)d_in[9];

    float* ws   = (float*)d_ws;
    float* dinv = ws + OFF_DINV;
    float* h1   = ws + OFF_H1;
    float* out1 = ws + OFF_OUT1;
    float* h2   = ws + OFF_H2;
    float* out2 = ws + OFF_OUT2;
    unsigned* pool = (unsigned*)(ws + OFF_POOL);

    hipMemsetAsync(dinv, 0, NN * 4, stream);
    hipMemsetAsync(pool, 0, 64 * 4, stream);

    k_deg  <<<(NE + 255) / 256, 256, 0, stream>>>(ei, (unsigned*)dinv);
    k_dinv <<<(NN + 255) / 256, 256, 0, stream>>>(dinv);
    k_gemm1<<<(NN + 255) / 256, 256, 0, stream>>>(x, W1, h1);
    k_loop1<<<(NN * F1 + 255) / 256, 256, 0, stream>>>(h1, dinv, out1);
    k_scat1<<<(NE * 4) / 256, 256, 0, stream>>>(ei, dinv, h1, out1);
    k_gemm2<<<(NN + 255) / 256, 256, 0, stream>>>(out1, b1, W2, h2);
    k_loop2<<<(NN * F2 + 255) / 256, 256, 0, stream>>>(h2, dinv, b2, out2);
    k_scat2<<<(NE * 8) / 256, 256, 0, stream>>>(ei, dinv, h2, out2);
    k_conv <<<(NN + NPB - 1) / NPB, 256, 0, stream>>>(out2, cw, pool);
    k_fc   <<<4, 256, 0, stream>>>(pool, cb, fw, fb, (float*)d_out);
}

// Round 2
// 1022.864 us; speedup vs baseline: 2.1228x; 2.1228x over previous
//
#include <hip/hip_runtime.h>
#include <hip/hip_bf16.h>

#define NN 100000
#define NE 3200000
#define FIN 256
#define F1 16
#define F2 32
#define CO 64
#define NC 1000

// workspace layout (float offsets)
#define OFF_DINV 0
#define OFF_CUR  100352
#define OFF_DEG  200704
#define OFF_ECOL 301056
#define OFF_H1S  3501056
#define OFF_OUT1 5101056
#define OFF_H2S  6701056
#define OFF_OUT2 3501056   /* aliases h1s+out1 (both dead when gath2 writes) */
#define OFF_POOL 9901056

__device__ __forceinline__ unsigned enc_f(float f) {
    unsigned u = __float_as_uint(f);
    return (u & 0x80000000u) ? ~u : (u | 0x80000000u);
}
__device__ __forceinline__ float dec_f(unsigned u) {
    return (u & 0x80000000u) ? __uint_as_float(u & 0x7fffffffu) : __uint_as_float(~u);
}

// ---------- K0: in-degree count (int atomics) ----------
__global__ void k_deg(const int* __restrict__ ei, unsigned* __restrict__ deg) {
    int e = blockIdx.x * 256 + threadIdx.x;
    if (e < NE) atomicAdd(&deg[ei[NE + e]], 1u);
}

// ---------- K1: single-block exclusive scan -> cursor (=rowptr), dinv ----------
#define PER_T 98
__global__ __launch_bounds__(1024) void k_scan(const unsigned* __restrict__ deg,
                                               unsigned* __restrict__ cursor,
                                               float* __restrict__ dinv) {
    __shared__ unsigned S[1024];
    int t = threadIdx.x;
    int base = t * PER_T;
    unsigned sum = 0;
    for (int j = 0; j < PER_T; ++j) {
        int i = base + j;
        if (i < NN) sum += deg[i];
    }
    S[t] = sum;
    __syncthreads();
    for (int off = 1; off < 1024; off <<= 1) {
        unsigned v = (t >= off) ? S[t - off] : 0u;
        __syncthreads();
        S[t] += v;
        __syncthreads();
    }
    unsigned run = (t > 0) ? S[t - 1] : 0u;
    for (int j = 0; j < PER_T; ++j) {
        int i = base + j;
        if (i < NN) {
            unsigned d = deg[i];
            cursor[i] = run;                    // rowptr[i]
            dinv[i] = rsqrtf((float)(d + 1u));
            run += d;
        }
    }
}

// ---------- K2: CSR bucket fill (after: cursor[i] == rowptr[i+1]) ----------
__global__ void k_fill(const int* __restrict__ ei, unsigned* __restrict__ cursor,
                       int* __restrict__ ecol) {
    int e = blockIdx.x * 256 + threadIdx.x;
    if (e < NE) {
        int dst = ei[NE + e];
        unsigned pos = atomicAdd(&cursor[dst], 1u);
        ecol[pos] = ei[e];
    }
}

// ---------- K3: h1s = (X @ W1) * dinv[row]  (100000x256 @ 256x16) ----------
__global__ __launch_bounds__(256) void k_gemm1(const float* __restrict__ X,
                                               const float* __restrict__ W1,
                                               const float* __restrict__ dinv,
                                               float* __restrict__ h1s) {
    __shared__ float Xs[32][257];
    __shared__ float4 Ws[1024];   // W1 as float4: [256 k][4 colgroups]
    int tid = threadIdx.x;
    const float4* W14 = (const float4*)W1;
    for (int i = tid; i < 1024; i += 256) Ws[i] = W14[i];

    int rowbase = blockIdx.x * 256;
    int q  = tid >> 2;      // 0..63
    int cg = tid & 3;       // col group
    float4 acc[4] = {};

    for (int kt = 0; kt < 8; ++kt) {
        __syncthreads();
        #pragma unroll
        for (int it = 0; it < 8; ++it) {
            int fl = tid + it * 256;
            int rl = fl >> 3;
            int c4 = (fl & 7) << 2;
            int gr = rowbase + rl;
            float4 v = make_float4(0.f, 0.f, 0.f, 0.f);
            if (gr < NN) v = *(const float4*)(X + (size_t)gr * FIN + kt * 32 + c4);
            Xs[c4 + 0][rl] = v.x;
            Xs[c4 + 1][rl] = v.y;
            Xs[c4 + 2][rl] = v.z;
            Xs[c4 + 3][rl] = v.w;
        }
        __syncthreads();
        #pragma unroll
        for (int kk = 0; kk < 32; ++kk) {
            float4 w4 = Ws[(kt * 32 + kk) * 4 + cg];
            #pragma unroll
            for (int m = 0; m < 4; ++m) {
                float xv = Xs[kk][q + 64 * m];
                acc[m].x += xv * w4.x;
                acc[m].y += xv * w4.y;
                acc[m].z += xv * w4.z;
                acc[m].w += xv * w4.w;
            }
        }
    }
    #pragma unroll
    for (int m = 0; m < 4; ++m) {
        int r = rowbase + q + 64 * m;
        if (r < NN) {
            float dv = dinv[r];
            acc[m].x *= dv; acc[m].y *= dv; acc[m].z *= dv; acc[m].w *= dv;
            *(float4*)(h1s + (size_t)r * F1 + cg * 4) = acc[m];
        }
    }
}

// ---------- K4: gather layer 1: out1 = dinv*(sum h1s[nbr] + h1s[self]) ----------
__global__ __launch_bounds__(256) void k_gath1(const unsigned* __restrict__ cursor,
                                               const int* __restrict__ ecol,
                                               const float* __restrict__ dinv,
                                               const float* __restrict__ h1s,
                                               float* __restrict__ out1) {
    int tid = threadIdx.x;
    int node = blockIdx.x * 16 + (tid >> 4);
    int f = tid & 15;
    if (node >= NN) return;
    unsigned s = node ? cursor[node - 1] : 0u;
    unsigned e = cursor[node];
    float acc = h1s[(size_t)node * F1 + f];
    for (unsigned j = s; j < e; ++j) {
        int c = ecol[j];
        acc += h1s[(size_t)c * F1 + f];
    }
    out1[(size_t)node * F1 + f] = acc * dinv[node];
}

// ---------- K5: h2s = (relu(out1 + b1) @ W2) * dinv[row]  (16 -> 32) ----------
__global__ __launch_bounds__(256) void k_gemm2(const float* __restrict__ out1,
                                               const float* __restrict__ b1,
                                               const float* __restrict__ W2,
                                               const float* __restrict__ dinv,
                                               float* __restrict__ h2s) {
    __shared__ float4 Ws[128];  // W2 [16][8] float4
    __shared__ float B1[16];
    int tid = threadIdx.x;
    if (tid < 128) Ws[tid] = ((const float4*)W2)[tid];
    if (tid < 16) B1[tid] = b1[tid];
    __syncthreads();
    int n = blockIdx.x * 256 + tid;
    if (n >= NN) return;
    float r[16];
    #pragma unroll
    for (int f4 = 0; f4 < 4; ++f4) {
        float4 v = *(const float4*)(out1 + (size_t)n * F1 + f4 * 4);
        r[f4 * 4 + 0] = fmaxf(v.x + B1[f4 * 4 + 0], 0.f);
        r[f4 * 4 + 1] = fmaxf(v.y + B1[f4 * 4 + 1], 0.f);
        r[f4 * 4 + 2] = fmaxf(v.z + B1[f4 * 4 + 2], 0.f);
        r[f4 * 4 + 3] = fmaxf(v.w + B1[f4 * 4 + 3], 0.f);
    }
    float dv = dinv[n];
    #pragma unroll
    for (int cg = 0; cg < 8; ++cg) {
        float4 a = make_float4(0.f, 0.f, 0.f, 0.f);
        #pragma unroll
        for (int fi = 0; fi < 16; ++fi) {
            float4 w = Ws[fi * 8 + cg];
            a.x += r[fi] * w.x;
            a.y += r[fi] * w.y;
            a.z += r[fi] * w.z;
            a.w += r[fi] * w.w;
        }
        a.x *= dv; a.y *= dv; a.z *= dv; a.w *= dv;
        *(float4*)(h2s + (size_t)n * F2 + cg * 4) = a;
    }
}

// ---------- K6: gather layer 2 (+ b2) ----------
__global__ __launch_bounds__(256) void k_gath2(const unsigned* __restrict__ cursor,
                                               const int* __restrict__ ecol,
                                               const float* __restrict__ dinv,
                                               const float* __restrict__ b2,
                                               const float* __restrict__ h2s,
                                               float* __restrict__ out2) {
    int tid = threadIdx.x;
    int node = blockIdx.x * 8 + (tid >> 5);
    int f = tid & 31;
    if (node >= NN) return;
    unsigned s = node ? cursor[node - 1] : 0u;
    unsigned e = cursor[node];
    float acc = h2s[(size_t)node * F2 + f];
    for (unsigned j = s; j < e; ++j) {
        int c = ecol[j];
        acc += h2s[(size_t)c * F2 + f];
    }
    out2[(size_t)node * F2 + f] = acc * dinv[node] + b2[f];
}

// ---------- K7: conv1d(32->64, k=3, pad 1) + global max (bias deferred) ----------
#define NPB 256
__global__ __launch_bounds__(256) void k_conv(const float* __restrict__ h2f,
                                              const float* __restrict__ cw,
                                              unsigned* __restrict__ pool) {
    __shared__ float Hs[NPB + 2][33];
    __shared__ float Wt[3 * 32 * 64];   // [k][ci][o]
    __shared__ float4 Ms[4][16];
    int tid = threadIdx.x;
    int base = blockIdx.x * NPB;
    for (int idx = tid; idx < 6144; idx += 256) {
        int o = idx / 96, r = idx % 96, ci = r / 3, k = r % 3;
        Wt[(k * 32 + ci) * 64 + o] = cw[idx];
    }
    for (int idx = tid; idx < (NPB + 2) * 8; idx += 256) {
        int j = idx >> 3, c4 = (idx & 7) << 2;
        int g = base + j - 1;
        float4 v = make_float4(0.f, 0.f, 0.f, 0.f);
        if (g >= 0 && g < NN) v = *(const float4*)(h2f + (size_t)g * F2 + c4);
        Hs[j][c4 + 0] = v.x;
        Hs[j][c4 + 1] = v.y;
        Hs[j][c4 + 2] = v.z;
        Hs[j][c4 + 3] = v.w;
    }
    __syncthreads();

    int o4 = (tid & 15) * 4;
    int ng = tid >> 4;
    float4 acc[16] = {};
    for (int ci = 0; ci < 32; ++ci) {
        float h[18];
        #pragma unroll
        for (int j = 0; j < 18; ++j) h[j] = Hs[ng * 16 + j][ci];
        #pragma unroll
        for (int k = 0; k < 3; ++k) {
            float4 w = *(const float4*)&Wt[(k * 32 + ci) * 64 + o4];
            #pragma unroll
            for (int i = 0; i < 16; ++i) {
                float hv = h[i + k];
                acc[i].x += hv * w.x;
                acc[i].y += hv * w.y;
                acc[i].z += hv * w.z;
                acc[i].w += hv * w.w;
            }
        }
    }
    const float NI = -3.0e38f;
    float4 m4 = make_float4(NI, NI, NI, NI);
    #pragma unroll
    for (int i = 0; i < 16; ++i) {
        if (base + ng * 16 + i < NN) {
            m4.x = fmaxf(m4.x, acc[i].x);
            m4.y = fmaxf(m4.y, acc[i].y);
            m4.z = fmaxf(m4.z, acc[i].z);
            m4.w = fmaxf(m4.w, acc[i].w);
        }
    }
    #pragma unroll
    for (int off = 16; off <= 32; off <<= 1) {
        m4.x = fmaxf(m4.x, __shfl_xor(m4.x, off));
        m4.y = fmaxf(m4.y, __shfl_xor(m4.y, off));
        m4.z = fmaxf(m4.z, __shfl_xor(m4.z, off));
        m4.w = fmaxf(m4.w, __shfl_xor(m4.w, off));
    }
    int lane = tid & 63, wv = tid >> 6;
    if (lane < 16) Ms[wv][lane] = m4;
    __syncthreads();
    if (tid < 16) {
        float4 a = Ms[0][tid], b = Ms[1][tid], c = Ms[2][tid], d = Ms[3][tid];
        a.x = fmaxf(fmaxf(a.x, b.x), fmaxf(c.x, d.x));
        a.y = fmaxf(fmaxf(a.y, b.y), fmaxf(c.y, d.y));
        a.z = fmaxf(fmaxf(a.z, b.z), fmaxf(c.z, d.z));
        a.w = fmaxf(fmaxf(a.w, b.w), fmaxf(c.w, d.w));
        int o = tid * 4;
        atomicMax(&pool[o + 0], enc_f(a.x));
        atomicMax(&pool[o + 1], enc_f(a.y));
        atomicMax(&pool[o + 2], enc_f(a.z));
        atomicMax(&pool[o + 3], enc_f(a.w));
    }
}

// ---------- K8: out = (pooled + conv_b) @ fc_w^T + fc_b ----------
__global__ void k_fc(const unsigned* __restrict__ pool, const float* __restrict__ cb,
                     const float* __restrict__ fw, const float* __restrict__ fb,
                     float* __restrict__ out) {
    __shared__ float P[64];
    int tid = threadIdx.x;
    if (tid < 64) P[tid] = dec_f(pool[tid]) + cb[tid];
    __syncthreads();
    int j = blockIdx.x * 256 + tid;
    if (j >= NC) return;
    float s = fb[j];
    const float4* wr = (const float4*)(fw + (size_t)j * CO);
    #pragma unroll
    for (int c = 0; c < 16; ++c) {
        float4 w = wr[c];
        s += P[c * 4 + 0] * w.x + P[c * 4 + 1] * w.y +
             P[c * 4 + 2] * w.z + P[c * 4 + 3] * w.w;
    }
    out[j] = s;
}

extern "C" void kernel_launch(void* const* d_in, const int* in_sizes, int n_in,
                              void* d_out, int out_size, void* d_ws, size_t ws_size,
                              hipStream_t stream) {
    const float* x  = (const float*)d_in[0];
    const int*   ei = (const int*)d_in[1];
    const float* W1 = (const float*)d_in[2];
    const float* b1 = (const float*)d_in[3];
    const float* W2 = (const float*)d_in[4];
    const float* b2 = (const float*)d_in[5];
    const float* cw = (const float*)d_in[6];
    const float* cb = (const float*)d_in[7];
    const float* fw = (const float*)d_in[8];
    const float* fb = (const float*)d_in[9];

    float* ws = (float*)d_ws;
    float*    dinv   = ws + OFF_DINV;
    unsigned* cursor = (unsigned*)(ws + OFF_CUR);
    unsigned* deg    = (unsigned*)(ws + OFF_DEG);
    int*      ecol   = (int*)(ws + OFF_ECOL);
    float*    h1s    = ws + OFF_H1S;
    float*    out1   = ws + OFF_OUT1;
    float*    h2s    = ws + OFF_H2S;
    float*    out2   = ws + OFF_OUT2;
    unsigned* pool   = (unsigned*)(ws + OFF_POOL);

    hipMemsetAsync(deg, 0, NN * 4, stream);
    hipMemsetAsync(pool, 0, 64 * 4, stream);

    k_deg  <<<(NE + 255) / 256, 256, 0, stream>>>(ei, deg);
    k_scan <<<1, 1024, 0, stream>>>(deg, cursor, dinv);
    k_fill <<<(NE + 255) / 256, 256, 0, stream>>>(ei, cursor, ecol);
    k_gemm1<<<(NN + 255) / 256, 256, 0, stream>>>(x, W1, dinv, h1s);
    k_gath1<<<(NN + 15) / 16, 256, 0, stream>>>(cursor, ecol, dinv, h1s, out1);
    k_gemm2<<<(NN + 255) / 256, 256, 0, stream>>>(out1, b1, W2, dinv, h2s);
    k_gath2<<<(NN + 7) / 8, 256, 0, stream>>>(cursor, ecol, dinv, b2, h2s, out2);
    k_conv <<<(NN + NPB - 1) / NPB, 256, 0, stream>>>(out2, cw, pool);
    k_fc   <<<4, 256, 0, stream>>>(pool, cb, fw, fb, (float*)d_out);
}

// Round 3
// 655.884 us; speedup vs baseline: 3.3105x; 1.5595x over previous
//
#include <hip/hip_runtime.h>
#include <hip/hip_bf16.h>

#define NN 100000
#define NE 3200000
#define FIN 256
#define F1 16
#define F2 32
#define CO 64
#define NC 1000
#define NBLK 391   /* ceil(NN/256) */

// workspace layout (float offsets)
#define OFF_DINV 0
#define OFF_CUR  100352
#define OFF_DEG  200704
#define OFF_ECOL 301056
#define OFF_H1S  3501056
#define OFF_OUT1 5101056
#define OFF_H2S  6701056
#define OFF_OUT2 3501056   /* aliases h1s+out1 (both dead when gath2 writes) */
#define OFF_POOL 9901056
#define OFF_BSUM 9901184

__device__ __forceinline__ unsigned enc_f(float f) {
    unsigned u = __float_as_uint(f);
    return (u & 0x80000000u) ? ~u : (u | 0x80000000u);
}
__device__ __forceinline__ float dec_f(unsigned u) {
    return (u & 0x80000000u) ? __uint_as_float(u & 0x7fffffffu) : __uint_as_float(~u);
}

// ---------- K0: in-degree count (no-return int atomics, 4 edges/thread) ----------
__global__ void k_deg(const int* __restrict__ ei, unsigned* __restrict__ deg) {
    int base = blockIdx.x * 1024 + threadIdx.x;
    #pragma unroll
    for (int k = 0; k < 4; ++k)
        atomicAdd(&deg[ei[NE + base + k * 256]], 1u);
}

// ---------- K1a: per-block degree sums ----------
__global__ void k_bsum(const unsigned* __restrict__ deg, unsigned* __restrict__ bsum) {
    __shared__ unsigned W[4];
    int t = threadIdx.x;
    int i = blockIdx.x * 256 + t;
    unsigned d = (i < NN) ? deg[i] : 0u;
    #pragma unroll
    for (int off = 1; off < 64; off <<= 1) d += __shfl_xor(d, off);
    if ((t & 63) == 0) W[t >> 6] = d;
    __syncthreads();
    if (t == 0) bsum[blockIdx.x] = W[0] + W[1] + W[2] + W[3];
}

// ---------- K1b: exclusive scan of block sums (1 block) ----------
__global__ __launch_bounds__(512) void k_bscan(unsigned* __restrict__ bsum) {
    __shared__ unsigned S[512];
    int t = threadIdx.x;
    unsigned v = (t < NBLK) ? bsum[t] : 0u;
    S[t] = v;
    __syncthreads();
    for (int off = 1; off < 512; off <<= 1) {
        unsigned u = (t >= off) ? S[t - off] : 0u;
        __syncthreads();
        S[t] += u;
        __syncthreads();
    }
    if (t < NBLK) bsum[t] = S[t] - v;   // exclusive prefix
}

// ---------- K1c: per-block scan -> cursor (=rowptr), dinv ----------
__global__ void k_cscan(const unsigned* __restrict__ deg, const unsigned* __restrict__ bsum,
                        unsigned* __restrict__ cursor, float* __restrict__ dinv) {
    __shared__ unsigned S[256];
    int t = threadIdx.x;
    int i = blockIdx.x * 256 + t;
    unsigned d = (i < NN) ? deg[i] : 0u;
    S[t] = d;
    __syncthreads();
    for (int off = 1; off < 256; off <<= 1) {
        unsigned u = (t >= off) ? S[t - off] : 0u;
        __syncthreads();
        S[t] += u;
        __syncthreads();
    }
    if (i < NN) {
        cursor[i] = bsum[blockIdx.x] + S[t] - d;   // rowptr[i]
        dinv[i] = rsqrtf((float)(d + 1u));
    }
}

// ---------- K2: CSR bucket fill, 4 edges/thread (after: cursor[i]==rowptr[i+1]) ----------
__global__ void k_fill(const int* __restrict__ ei, unsigned* __restrict__ cursor,
                       int* __restrict__ ecol) {
    int base = blockIdx.x * 1024 + threadIdx.x;
    int d0 = ei[NE + base], d1 = ei[NE + base + 256],
        d2 = ei[NE + base + 512], d3 = ei[NE + base + 768];
    int s0 = ei[base], s1 = ei[base + 256], s2 = ei[base + 512], s3 = ei[base + 768];
    unsigned p0 = atomicAdd(&cursor[d0], 1u);
    unsigned p1 = atomicAdd(&cursor[d1], 1u);
    unsigned p2 = atomicAdd(&cursor[d2], 1u);
    unsigned p3 = atomicAdd(&cursor[d3], 1u);
    ecol[p0] = s0; ecol[p1] = s1; ecol[p2] = s2; ecol[p3] = s3;
}

// ---------- K3: h1s = (X @ W1) * dinv[row] ----------
__global__ __launch_bounds__(256) void k_gemm1(const float* __restrict__ X,
                                               const float* __restrict__ W1,
                                               const float* __restrict__ dinv,
                                               float* __restrict__ h1s) {
    __shared__ float Xs[32][257];
    __shared__ float4 Ws[1024];
    int tid = threadIdx.x;
    const float4* W14 = (const float4*)W1;
    for (int i = tid; i < 1024; i += 256) Ws[i] = W14[i];

    int rowbase = blockIdx.x * 256;
    int q  = tid >> 2;
    int cg = tid & 3;
    float4 acc[4] = {};

    for (int kt = 0; kt < 8; ++kt) {
        __syncthreads();
        #pragma unroll
        for (int it = 0; it < 8; ++it) {
            int fl = tid + it * 256;
            int rl = fl >> 3;
            int c4 = (fl & 7) << 2;
            int gr = rowbase + rl;
            float4 v = make_float4(0.f, 0.f, 0.f, 0.f);
            if (gr < NN) v = *(const float4*)(X + (size_t)gr * FIN + kt * 32 + c4);
            Xs[c4 + 0][rl] = v.x;
            Xs[c4 + 1][rl] = v.y;
            Xs[c4 + 2][rl] = v.z;
            Xs[c4 + 3][rl] = v.w;
        }
        __syncthreads();
        #pragma unroll
        for (int kk = 0; kk < 32; ++kk) {
            float4 w4 = Ws[(kt * 32 + kk) * 4 + cg];
            #pragma unroll
            for (int m = 0; m < 4; ++m) {
                float xv = Xs[kk][q + 64 * m];
                acc[m].x += xv * w4.x;
                acc[m].y += xv * w4.y;
                acc[m].z += xv * w4.z;
                acc[m].w += xv * w4.w;
            }
        }
    }
    #pragma unroll
    for (int m = 0; m < 4; ++m) {
        int r = rowbase + q + 64 * m;
        if (r < NN) {
            float dv = dinv[r];
            acc[m].x *= dv; acc[m].y *= dv; acc[m].z *= dv; acc[m].w *= dv;
            *(float4*)(h1s + (size_t)r * F1 + cg * 4) = acc[m];
        }
    }
}

// ---------- K4: gather layer 1 — one node per wave, 8 neighbors in flight ----------
__global__ __launch_bounds__(256) void k_gath1(const unsigned* __restrict__ cursor,
                                               const int* __restrict__ ecol,
                                               const float* __restrict__ dinv,
                                               const float* __restrict__ h1s,
                                               float* __restrict__ out1) {
    int tid = threadIdx.x;
    int node = blockIdx.x * 4 + (tid >> 6);
    if (node >= NN) return;
    int lane = tid & 63;
    int f = lane & 15, nb = lane >> 4;            // 4 neighbor groups
    unsigned s = node ? cursor[node - 1] : 0u;
    unsigned e = cursor[node];
    float acc = (nb == 0) ? h1s[(size_t)node * F1 + f] : 0.f;
    unsigned j = s + nb;
    for (; j + 4 < e; j += 8) {
        int c0 = ecol[j], c1 = ecol[j + 4];
        acc += h1s[(size_t)c0 * F1 + f];
        acc += h1s[(size_t)c1 * F1 + f];
    }
    if (j < e) acc += h1s[(size_t)ecol[j] * F1 + f];
    acc += __shfl_xor(acc, 16);
    acc += __shfl_xor(acc, 32);
    if (lane < 16) out1[(size_t)node * F1 + f] = acc * dinv[node];
}

// ---------- K5: h2s = (relu(out1 + b1) @ W2) * dinv[row] ----------
__global__ __launch_bounds__(256) void k_gemm2(const float* __restrict__ out1,
                                               const float* __restrict__ b1,
                                               const float* __restrict__ W2,
                                               const float* __restrict__ dinv,
                                               float* __restrict__ h2s) {
    __shared__ float4 Ws[128];
    __shared__ float B1[16];
    int tid = threadIdx.x;
    if (tid < 128) Ws[tid] = ((const float4*)W2)[tid];
    if (tid < 16) B1[tid] = b1[tid];
    __syncthreads();
    int n = blockIdx.x * 256 + tid;
    if (n >= NN) return;
    float r[16];
    #pragma unroll
    for (int f4 = 0; f4 < 4; ++f4) {
        float4 v = *(const float4*)(out1 + (size_t)n * F1 + f4 * 4);
        r[f4 * 4 + 0] = fmaxf(v.x + B1[f4 * 4 + 0], 0.f);
        r[f4 * 4 + 1] = fmaxf(v.y + B1[f4 * 4 + 1], 0.f);
        r[f4 * 4 + 2] = fmaxf(v.z + B1[f4 * 4 + 2], 0.f);
        r[f4 * 4 + 3] = fmaxf(v.w + B1[f4 * 4 + 3], 0.f);
    }
    float dv = dinv[n];
    #pragma unroll
    for (int cg = 0; cg < 8; ++cg) {
        float4 a = make_float4(0.f, 0.f, 0.f, 0.f);
        #pragma unroll
        for (int fi = 0; fi < 16; ++fi) {
            float4 w = Ws[fi * 8 + cg];
            a.x += r[fi] * w.x;
            a.y += r[fi] * w.y;
            a.z += r[fi] * w.z;
            a.w += r[fi] * w.w;
        }
        a.x *= dv; a.y *= dv; a.z *= dv; a.w *= dv;
        *(float4*)(h2s + (size_t)n * F2 + cg * 4) = a;
    }
}

// ---------- K6: gather layer 2 — one node per wave, 8 neighbors in flight ----------
__global__ __launch_bounds__(256) void k_gath2(const unsigned* __restrict__ cursor,
                                               const int* __restrict__ ecol,
                                               const float* __restrict__ dinv,
                                               const float* __restrict__ b2,
                                               const float* __restrict__ h2s,
                                               float* __restrict__ out2) {
    int tid = threadIdx.x;
    int node = blockIdx.x * 4 + (tid >> 6);
    if (node >= NN) return;
    int lane = tid & 63;
    int f = lane & 31, nb = lane >> 5;            // 2 neighbor groups
    unsigned s = node ? cursor[node - 1] : 0u;
    unsigned e = cursor[node];
    float acc = (nb == 0) ? h2s[(size_t)node * F2 + f] : 0.f;
    unsigned j = s + nb;
    for (; j + 6 < e; j += 8) {
        int c0 = ecol[j], c1 = ecol[j + 2], c2 = ecol[j + 4], c3 = ecol[j + 6];
        acc += h2s[(size_t)c0 * F2 + f];
        acc += h2s[(size_t)c1 * F2 + f];
        acc += h2s[(size_t)c2 * F2 + f];
        acc += h2s[(size_t)c3 * F2 + f];
    }
    for (; j < e; j += 2) acc += h2s[(size_t)ecol[j] * F2 + f];
    acc += __shfl_xor(acc, 32);
    if (lane < 32) out2[(size_t)node * F2 + f] = acc * dinv[node] + b2[f];
}

// ---------- K7: conv1d(32->64, k=3, pad 1) + global max ----------
#define NPB 256
__global__ __launch_bounds__(256) void k_conv(const float* __restrict__ h2f,
                                              const float* __restrict__ cw,
                                              unsigned* __restrict__ pool) {
    __shared__ float Hs[NPB + 2][33];
    __shared__ float Wt[3 * 32 * 64];
    __shared__ float4 Ms[4][16];
    int tid = threadIdx.x;
    int base = blockIdx.x * NPB;
    for (int idx = tid; idx < 6144; idx += 256) {
        int o = idx / 96, r = idx % 96, ci = r / 3, k = r % 3;
        Wt[(k * 32 + ci) * 64 + o] = cw[idx];
    }
    for (int idx = tid; idx < (NPB + 2) * 8; idx += 256) {
        int j = idx >> 3, c4 = (idx & 7) << 2;
        int g = base + j - 1;
        float4 v = make_float4(0.f, 0.f, 0.f, 0.f);
        if (g >= 0 && g < NN) v = *(const float4*)(h2f + (size_t)g * F2 + c4);
        Hs[j][c4 + 0] = v.x;
        Hs[j][c4 + 1] = v.y;
        Hs[j][c4 + 2] = v.z;
        Hs[j][c4 + 3] = v.w;
    }
    __syncthreads();

    int o4 = (tid & 15) * 4;
    int ng = tid >> 4;
    float4 acc[16] = {};
    for (int ci = 0; ci < 32; ++ci) {
        float h[18];
        #pragma unroll
        for (int j = 0; j < 18; ++j) h[j] = Hs[ng * 16 + j][ci];
        #pragma unroll
        for (int k = 0; k < 3; ++k) {
            float4 w = *(const float4*)&Wt[(k * 32 + ci) * 64 + o4];
            #pragma unroll
            for (int i = 0; i < 16; ++i) {
                float hv = h[i + k];
                acc[i].x += hv * w.x;
                acc[i].y += hv * w.y;
                acc[i].z += hv * w.z;
                acc[i].w += hv * w.w;
            }
        }
    }
    const float NI = -3.0e38f;
    float4 m4 = make_float4(NI, NI, NI, NI);
    #pragma unroll
    for (int i = 0; i < 16; ++i) {
        if (base + ng * 16 + i < NN) {
            m4.x = fmaxf(m4.x, acc[i].x);
            m4.y = fmaxf(m4.y, acc[i].y);
            m4.z = fmaxf(m4.z, acc[i].z);
            m4.w = fmaxf(m4.w, acc[i].w);
        }
    }
    #pragma unroll
    for (int off = 16; off <= 32; off <<= 1) {
        m4.x = fmaxf(m4.x, __shfl_xor(m4.x, off));
        m4.y = fmaxf(m4.y, __shfl_xor(m4.y, off));
        m4.z = fmaxf(m4.z, __shfl_xor(m4.z, off));
        m4.w = fmaxf(m4.w, __shfl_xor(m4.w, off));
    }
    int lane = tid & 63, wv = tid >> 6;
    if (lane < 16) Ms[wv][lane] = m4;
    __syncthreads();
    if (tid < 16) {
        float4 a = Ms[0][tid], b = Ms[1][tid], c = Ms[2][tid], d = Ms[3][tid];
        a.x = fmaxf(fmaxf(a.x, b.x), fmaxf(c.x, d.x));
        a.y = fmaxf(fmaxf(a.y, b.y), fmaxf(c.y, d.y));
        a.z = fmaxf(fmaxf(a.z, b.z), fmaxf(c.z, d.z));
        a.w = fmaxf(fmaxf(a.w, b.w), fmaxf(c.w, d.w));
        int o = tid * 4;
        atomicMax(&pool[o + 0], enc_f(a.x));
        atomicMax(&pool[o + 1], enc_f(a.y));
        atomicMax(&pool[o + 2], enc_f(a.z));
        atomicMax(&pool[o + 3], enc_f(a.w));
    }
}

// ---------- K8: out = (pooled + conv_b) @ fc_w^T + fc_b ----------
__global__ void k_fc(const unsigned* __restrict__ pool, const float* __restrict__ cb,
                     const float* __restrict__ fw, const float* __restrict__ fb,
                     float* __restrict__ out) {
    __shared__ float P[64];
    int tid = threadIdx.x;
    if (tid < 64) P[tid] = dec_f(pool[tid]) + cb[tid];
    __syncthreads();
    int j = blockIdx.x * 256 + tid;
    if (j >= NC) return;
    float s = fb[j];
    const float4* wr = (const float4*)(fw + (size_t)j * CO);
    #pragma unroll
    for (int c = 0; c < 16; ++c) {
        float4 w = wr[c];
        s += P[c * 4 + 0] * w.x + P[c * 4 + 1] * w.y +
             P[c * 4 + 2] * w.z + P[c * 4 + 3] * w.w;
    }
    out[j] = s;
}

extern "C" void kernel_launch(void* const* d_in, const int* in_sizes, int n_in,
                              void* d_out, int out_size, void* d_ws, size_t ws_size,
                              hipStream_t stream) {
    const float* x  = (const float*)d_in[0];
    const int*   ei = (const int*)d_in[1];
    const float* W1 = (const float*)d_in[2];
    const float* b1 = (const float*)d_in[3];
    const float* W2 = (const float*)d_in[4];
    const float* b2 = (const float*)d_in[5];
    const float* cw = (const float*)d_in[6];
    const float* cb = (const float*)d_in[7];
    const float* fw = (const float*)d_in[8];
    const float* fb = (const float*)d_in[9];

    float* ws = (float*)d_ws;
    float*    dinv   = ws + OFF_DINV;
    unsigned* cursor = (unsigned*)(ws + OFF_CUR);
    unsigned* deg    = (unsigned*)(ws + OFF_DEG);
    int*      ecol   = (int*)(ws + OFF_ECOL);
    float*    h1s    = ws + OFF_H1S;
    float*    out1   = ws + OFF_OUT1;
    float*    h2s    = ws + OFF_H2S;
    float*    out2   = ws + OFF_OUT2;
    unsigned* pool   = (unsigned*)(ws + OFF_POOL);
    unsigned* bsum   = (unsigned*)(ws + OFF_BSUM);

    hipMemsetAsync(deg, 0, NN * 4, stream);
    hipMemsetAsync(pool, 0, 64 * 4, stream);

    k_deg  <<<NE / 1024, 256, 0, stream>>>(ei, deg);            // 3125 blocks, no tail
    k_bsum <<<NBLK, 256, 0, stream>>>(deg, bsum);
    k_bscan<<<1, 512, 0, stream>>>(bsum);
    k_cscan<<<NBLK, 256, 0, stream>>>(deg, bsum, cursor, dinv);
    k_fill <<<NE / 1024, 256, 0, stream>>>(ei, cursor, ecol);   // 3125 blocks, no tail
    k_gemm1<<<(NN + 255) / 256, 256, 0, stream>>>(x, W1, dinv, h1s);
    k_gath1<<<(NN + 3) / 4, 256, 0, stream>>>(cursor, ecol, dinv, h1s, out1);
    k_gemm2<<<(NN + 255) / 256, 256, 0, stream>>>(out1, b1, W2, dinv, h2s);
    k_gath2<<<(NN + 3) / 4, 256, 0, stream>>>(cursor, ecol, dinv, b2, h2s, out2);
    k_conv <<<(NN + NPB - 1) / NPB, 256, 0, stream>>>(out2, cw, pool);
    k_fc   <<<4, 256, 0, stream>>>(pool, cb, fw, fb, (float*)d_out);
}

// Round 4
// 517.485 us; speedup vs baseline: 4.1959x; 1.2674x over previous
//
#include <hip/hip_runtime.h>
#include <hip/hip_bf16.h>

#define NN 100000
#define NE 3200000
#define FIN 256
#define F1 16
#define F2 32
#define CO 64
#define NC 1000
#define NBLK 391   /* ceil(NN/256) */
#define NPART 8
#define PSZ 12500  /* NN / NPART */

// workspace layout (float offsets)
#define OFF_DINV 0
#define OFF_CUR  100352
#define OFF_DEG  200704
#define OFF_ECOL 301056
#define OFF_H1S  3501056
#define OFF_OUT1 5101056
#define OFF_H2S  6701056
#define OFF_OUT2 3501056   /* aliases h1s+out1 (both dead when gath2 writes) */
#define OFF_POOL 9901056
#define OFF_BSUM 9901184

__device__ __forceinline__ unsigned enc_f(float f) {
    unsigned u = __float_as_uint(f);
    return (u & 0x80000000u) ? ~u : (u | 0x80000000u);
}
__device__ __forceinline__ float dec_f(unsigned u) {
    return (u & 0x80000000u) ? __uint_as_float(u & 0x7fffffffu) : __uint_as_float(~u);
}

// ---------- K0: in-degree count (no-return int atomics, 4 edges/thread) ----------
__global__ void k_deg(const int* __restrict__ ei, unsigned* __restrict__ deg) {
    int base = blockIdx.x * 1024 + threadIdx.x;
    #pragma unroll
    for (int k = 0; k < 4; ++k)
        atomicAdd(&deg[ei[NE + base + k * 256]], 1u);
}

// ---------- K1a: per-block degree sums ----------
__global__ void k_bsum(const unsigned* __restrict__ deg, unsigned* __restrict__ bsum) {
    __shared__ unsigned W[4];
    int t = threadIdx.x;
    int i = blockIdx.x * 256 + t;
    unsigned d = (i < NN) ? deg[i] : 0u;
    #pragma unroll
    for (int off = 1; off < 64; off <<= 1) d += __shfl_xor(d, off);
    if ((t & 63) == 0) W[t >> 6] = d;
    __syncthreads();
    if (t == 0) bsum[blockIdx.x] = W[0] + W[1] + W[2] + W[3];
}

// ---------- K1b: exclusive scan of block sums (1 block) ----------
__global__ __launch_bounds__(512) void k_bscan(unsigned* __restrict__ bsum) {
    __shared__ unsigned S[512];
    int t = threadIdx.x;
    unsigned v = (t < NBLK) ? bsum[t] : 0u;
    S[t] = v;
    __syncthreads();
    for (int off = 1; off < 512; off <<= 1) {
        unsigned u = (t >= off) ? S[t - off] : 0u;
        __syncthreads();
        S[t] += u;
        __syncthreads();
    }
    if (t < NBLK) bsum[t] = S[t] - v;   // exclusive prefix
}

// ---------- K1c: per-block scan -> cursor (=rowptr), dinv ----------
__global__ void k_cscan(const unsigned* __restrict__ deg, const unsigned* __restrict__ bsum,
                        unsigned* __restrict__ cursor, float* __restrict__ dinv) {
    __shared__ unsigned S[256];
    int t = threadIdx.x;
    int i = blockIdx.x * 256 + t;
    unsigned d = (i < NN) ? deg[i] : 0u;
    S[t] = d;
    __syncthreads();
    for (int off = 1; off < 256; off <<= 1) {
        unsigned u = (t >= off) ? S[t - off] : 0u;
        __syncthreads();
        S[t] += u;
        __syncthreads();
    }
    if (i < NN) {
        cursor[i] = bsum[blockIdx.x] + S[t] - d;   // rowptr[i]
        dinv[i] = rsqrtf((float)(d + 1u));
    }
}

// ---------- K2: XCD-partitioned CSR bucket fill ----------
// Block b handles only dst in partition (b&7); under %8 round-robin dispatch all
// writes from one XCD land in a contiguous 1.6 MB ecol slice that fits its L2,
// killing the 16x write amplification of fully-random 4B stores.
// (after: cursor[i] == rowptr[i+1])
__global__ void k_fill(const int* __restrict__ ei, unsigned* __restrict__ cursor,
                       int* __restrict__ ecol) {
    int part = blockIdx.x & 7;
    int chunk = blockIdx.x >> 3;
    int base = chunk * 1024 + threadIdx.x;
    int lo = part * PSZ, hi = lo + PSZ;
    #pragma unroll
    for (int k = 0; k < 4; ++k) {
        int e = base + k * 256;
        int dst = ei[NE + e];
        if (dst >= lo && dst < hi) {
            unsigned pos = atomicAdd(&cursor[dst], 1u);
            ecol[pos] = ei[e];
        }
    }
}

// ---------- K3: h1s = (X @ W1) * dinv[row] ----------
__global__ __launch_bounds__(256) void k_gemm1(const float* __restrict__ X,
                                               const float* __restrict__ W1,
                                               const float* __restrict__ dinv,
                                               float* __restrict__ h1s) {
    __shared__ float Xs[32][257];
    __shared__ float4 Ws[1024];
    int tid = threadIdx.x;
    const float4* W14 = (const float4*)W1;
    for (int i = tid; i < 1024; i += 256) Ws[i] = W14[i];

    int rowbase = blockIdx.x * 256;
    int q  = tid >> 2;
    int cg = tid & 3;
    float4 acc[4] = {};

    for (int kt = 0; kt < 8; ++kt) {
        __syncthreads();
        #pragma unroll
        for (int it = 0; it < 8; ++it) {
            int fl = tid + it * 256;
            int rl = fl >> 3;
            int c4 = (fl & 7) << 2;
            int gr = rowbase + rl;
            float4 v = make_float4(0.f, 0.f, 0.f, 0.f);
            if (gr < NN) v = *(const float4*)(X + (size_t)gr * FIN + kt * 32 + c4);
            Xs[c4 + 0][rl] = v.x;
            Xs[c4 + 1][rl] = v.y;
            Xs[c4 + 2][rl] = v.z;
            Xs[c4 + 3][rl] = v.w;
        }
        __syncthreads();
        #pragma unroll
        for (int kk = 0; kk < 32; ++kk) {
            float4 w4 = Ws[(kt * 32 + kk) * 4 + cg];
            #pragma unroll
            for (int m = 0; m < 4; ++m) {
                float xv = Xs[kk][q + 64 * m];
                acc[m].x += xv * w4.x;
                acc[m].y += xv * w4.y;
                acc[m].z += xv * w4.z;
                acc[m].w += xv * w4.w;
            }
        }
    }
    #pragma unroll
    for (int m = 0; m < 4; ++m) {
        int r = rowbase + q + 64 * m;
        if (r < NN) {
            float dv = dinv[r];
            acc[m].x *= dv; acc[m].y *= dv; acc[m].z *= dv; acc[m].w *= dv;
            *(float4*)(h1s + (size_t)r * F1 + cg * 4) = acc[m];
        }
    }
}

// ---------- K4: gather layer 1 — one node per wave, 8 neighbors in flight ----------
__global__ __launch_bounds__(256) void k_gath1(const unsigned* __restrict__ cursor,
                                               const int* __restrict__ ecol,
                                               const float* __restrict__ dinv,
                                               const float* __restrict__ h1s,
                                               float* __restrict__ out1) {
    int tid = threadIdx.x;
    int node = blockIdx.x * 4 + (tid >> 6);
    if (node >= NN) return;
    int lane = tid & 63;
    int f = lane & 15, nb = lane >> 4;            // 4 neighbor groups
    unsigned s = node ? cursor[node - 1] : 0u;
    unsigned e = cursor[node];
    float acc = (nb == 0) ? h1s[(size_t)node * F1 + f] : 0.f;
    unsigned j = s + nb;
    for (; j + 4 < e; j += 8) {
        int c0 = ecol[j], c1 = ecol[j + 4];
        acc += h1s[(size_t)c0 * F1 + f];
        acc += h1s[(size_t)c1 * F1 + f];
    }
    if (j < e) acc += h1s[(size_t)ecol[j] * F1 + f];
    acc += __shfl_xor(acc, 16);
    acc += __shfl_xor(acc, 32);
    if (lane < 16) out1[(size_t)node * F1 + f] = acc * dinv[node];
}

// ---------- K5: h2s = (relu(out1 + b1) @ W2) * dinv[row] ----------
__global__ __launch_bounds__(256) void k_gemm2(const float* __restrict__ out1,
                                               const float* __restrict__ b1,
                                               const float* __restrict__ W2,
                                               const float* __restrict__ dinv,
                                               float* __restrict__ h2s) {
    __shared__ float4 Ws[128];
    __shared__ float B1[16];
    int tid = threadIdx.x;
    if (tid < 128) Ws[tid] = ((const float4*)W2)[tid];
    if (tid < 16) B1[tid] = b1[tid];
    __syncthreads();
    int n = blockIdx.x * 256 + tid;
    if (n >= NN) return;
    float r[16];
    #pragma unroll
    for (int f4 = 0; f4 < 4; ++f4) {
        float4 v = *(const float4*)(out1 + (size_t)n * F1 + f4 * 4);
        r[f4 * 4 + 0] = fmaxf(v.x + B1[f4 * 4 + 0], 0.f);
        r[f4 * 4 + 1] = fmaxf(v.y + B1[f4 * 4 + 1], 0.f);
        r[f4 * 4 + 2] = fmaxf(v.z + B1[f4 * 4 + 2], 0.f);
        r[f4 * 4 + 3] = fmaxf(v.w + B1[f4 * 4 + 3], 0.f);
    }
    float dv = dinv[n];
    #pragma unroll
    for (int cg = 0; cg < 8; ++cg) {
        float4 a = make_float4(0.f, 0.f, 0.f, 0.f);
        #pragma unroll
        for (int fi = 0; fi < 16; ++fi) {
            float4 w = Ws[fi * 8 + cg];
            a.x += r[fi] * w.x;
            a.y += r[fi] * w.y;
            a.z += r[fi] * w.z;
            a.w += r[fi] * w.w;
        }
        a.x *= dv; a.y *= dv; a.z *= dv; a.w *= dv;
        *(float4*)(h2s + (size_t)n * F2 + cg * 4) = a;
    }
}

// ---------- K6: gather layer 2 — one node per wave, 8 neighbors in flight ----------
__global__ __launch_bounds__(256) void k_gath2(const unsigned* __restrict__ cursor,
                                               const int* __restrict__ ecol,
                                               const float* __restrict__ dinv,
                                               const float* __restrict__ b2,
                                               const float* __restrict__ h2s,
                                               float* __restrict__ out2) {
    int tid = threadIdx.x;
    int node = blockIdx.x * 4 + (tid >> 6);
    if (node >= NN) return;
    int lane = tid & 63;
    int f = lane & 31, nb = lane >> 5;            // 2 neighbor groups
    unsigned s = node ? cursor[node - 1] : 0u;
    unsigned e = cursor[node];
    float acc = (nb == 0) ? h2s[(size_t)node * F2 + f] : 0.f;
    unsigned j = s + nb;
    for (; j + 6 < e; j += 8) {
        int c0 = ecol[j], c1 = ecol[j + 2], c2 = ecol[j + 4], c3 = ecol[j + 6];
        acc += h2s[(size_t)c0 * F2 + f];
        acc += h2s[(size_t)c1 * F2 + f];
        acc += h2s[(size_t)c2 * F2 + f];
        acc += h2s[(size_t)c3 * F2 + f];
    }
    for (; j < e; j += 2) acc += h2s[(size_t)ecol[j] * F2 + f];
    acc += __shfl_xor(acc, 32);
    if (lane < 32) out2[(size_t)node * F2 + f] = acc * dinv[node] + b2[f];
}

// ---------- K7: conv1d(32->64, k=3, pad 1) + global max ----------
#define NPB 256
__global__ __launch_bounds__(256) void k_conv(const float* __restrict__ h2f,
                                              const float* __restrict__ cw,
                                              unsigned* __restrict__ pool) {
    __shared__ float Hs[NPB + 2][33];
    __shared__ float Wt[3 * 32 * 64];
    __shared__ float4 Ms[4][16];
    int tid = threadIdx.x;
    int base = blockIdx.x * NPB;
    for (int idx = tid; idx < 6144; idx += 256) {
        int o = idx / 96, r = idx % 96, ci = r / 3, k = r % 3;
        Wt[(k * 32 + ci) * 64 + o] = cw[idx];
    }
    for (int idx = tid; idx < (NPB + 2) * 8; idx += 256) {
        int j = idx >> 3, c4 = (idx & 7) << 2;
        int g = base + j - 1;
        float4 v = make_float4(0.f, 0.f, 0.f, 0.f);
        if (g >= 0 && g < NN) v = *(const float4*)(h2f + (size_t)g * F2 + c4);
        Hs[j][c4 + 0] = v.x;
        Hs[j][c4 + 1] = v.y;
        Hs[j][c4 + 2] = v.z;
        Hs[j][c4 + 3] = v.w;
    }
    __syncthreads();

    int o4 = (tid & 15) * 4;
    int ng = tid >> 4;
    float4 acc[16] = {};
    for (int ci = 0; ci < 32; ++ci) {
        float h[18];
        #pragma unroll
        for (int j = 0; j < 18; ++j) h[j] = Hs[ng * 16 + j][ci];
        #pragma unroll
        for (int k = 0; k < 3; ++k) {
            float4 w = *(const float4*)&Wt[(k * 32 + ci) * 64 + o4];
            #pragma unroll
            for (int i = 0; i < 16; ++i) {
                float hv = h[i + k];
                acc[i].x += hv * w.x;
                acc[i].y += hv * w.y;
                acc[i].z += hv * w.z;
                acc[i].w += hv * w.w;
            }
        }
    }
    const float NI = -3.0e38f;
    float4 m4 = make_float4(NI, NI, NI, NI);
    #pragma unroll
    for (int i = 0; i < 16; ++i) {
        if (base + ng * 16 + i < NN) {
            m4.x = fmaxf(m4.x, acc[i].x);
            m4.y = fmaxf(m4.y, acc[i].y);
            m4.z = fmaxf(m4.z, acc[i].z);
            m4.w = fmaxf(m4.w, acc[i].w);
        }
    }
    #pragma unroll
    for (int off = 16; off <= 32; off <<= 1) {
        m4.x = fmaxf(m4.x, __shfl_xor(m4.x, off));
        m4.y = fmaxf(m4.y, __shfl_xor(m4.y, off));
        m4.z = fmaxf(m4.z, __shfl_xor(m4.z, off));
        m4.w = fmaxf(m4.w, __shfl_xor(m4.w, off));
    }
    int lane = tid & 63, wv = tid >> 6;
    if (lane < 16) Ms[wv][lane] = m4;
    __syncthreads();
    if (tid < 16) {
        float4 a = Ms[0][tid], b = Ms[1][tid], c = Ms[2][tid], d = Ms[3][tid];
        a.x = fmaxf(fmaxf(a.x, b.x), fmaxf(c.x, d.x));
        a.y = fmaxf(fmaxf(a.y, b.y), fmaxf(c.y, d.y));
        a.z = fmaxf(fmaxf(a.z, b.z), fmaxf(c.z, d.z));
        a.w = fmaxf(fmaxf(a.w, b.w), fmaxf(c.w, d.w));
        int o = tid * 4;
        atomicMax(&pool[o + 0], enc_f(a.x));
        atomicMax(&pool[o + 1], enc_f(a.y));
        atomicMax(&pool[o + 2], enc_f(a.z));
        atomicMax(&pool[o + 3], enc_f(a.w));
    }
}

// ---------- K8: out = (pooled + conv_b) @ fc_w^T + fc_b ----------
__global__ void k_fc(const unsigned* __restrict__ pool, const float* __restrict__ cb,
                     const float* __restrict__ fw, const float* __restrict__ fb,
                     float* __restrict__ out) {
    __shared__ float P[64];
    int tid = threadIdx.x;
    if (tid < 64) P[tid] = dec_f(pool[tid]) + cb[tid];
    __syncthreads();
    int j = blockIdx.x * 256 + tid;
    if (j >= NC) return;
    float s = fb[j];
    const float4* wr = (const float4*)(fw + (size_t)j * CO);
    #pragma unroll
    for (int c = 0; c < 16; ++c) {
        float4 w = wr[c];
        s += P[c * 4 + 0] * w.x + P[c * 4 + 1] * w.y +
             P[c * 4 + 2] * w.z + P[c * 4 + 3] * w.w;
    }
    out[j] = s;
}

extern "C" void kernel_launch(void* const* d_in, const int* in_sizes, int n_in,
                              void* d_out, int out_size, void* d_ws, size_t ws_size,
                              hipStream_t stream) {
    const float* x  = (const float*)d_in[0];
    const int*   ei = (const int*)d_in[1];
    const float* W1 = (const float*)d_in[2];
    const float* b1 = (const float*)d_in[3];
    const float* W2 = (const float*)d_in[4];
    const float* b2 = (const float*)d_in[5];
    const float* cw = (const float*)d_in[6];
    const float* cb = (const float*)d_in[7];
    const float* fw = (const float*)d_in[8];
    const float* fb = (const float*)d_in[9];

    float* ws = (float*)d_ws;
    float*    dinv   = ws + OFF_DINV;
    unsigned* cursor = (unsigned*)(ws + OFF_CUR);
    unsigned* deg    = (unsigned*)(ws + OFF_DEG);
    int*      ecol   = (int*)(ws + OFF_ECOL);
    float*    h1s    = ws + OFF_H1S;
    float*    out1   = ws + OFF_OUT1;
    float*    h2s    = ws + OFF_H2S;
    float*    out2   = ws + OFF_OUT2;
    unsigned* pool   = (unsigned*)(ws + OFF_POOL);
    unsigned* bsum   = (unsigned*)(ws + OFF_BSUM);

    hipMemsetAsync(deg, 0, NN * 4, stream);
    hipMemsetAsync(pool, 0, 64 * 4, stream);

    k_deg  <<<NE / 1024, 256, 0, stream>>>(ei, deg);                 // 3125 blocks
    k_bsum <<<NBLK, 256, 0, stream>>>(deg, bsum);
    k_bscan<<<1, 512, 0, stream>>>(bsum);
    k_cscan<<<NBLK, 256, 0, stream>>>(deg, bsum, cursor, dinv);
    k_fill <<<(NE / 1024) * NPART, 256, 0, stream>>>(ei, cursor, ecol); // 25000 blocks
    k_gemm1<<<(NN + 255) / 256, 256, 0, stream>>>(x, W1, dinv, h1s);
    k_gath1<<<(NN + 3) / 4, 256, 0, stream>>>(cursor, ecol, dinv, h1s, out1);
    k_gemm2<<<(NN + 255) / 256, 256, 0, stream>>>(out1, b1, W2, dinv, h2s);
    k_gath2<<<(NN + 3) / 4, 256, 0, stream>>>(cursor, ecol, dinv, b2, h2s, out2);
    k_conv <<<(NN + NPB - 1) / NPB, 256, 0, stream>>>(out2, cw, pool);
    k_fc   <<<4, 256, 0, stream>>>(pool, cb, fw, fb, (float*)d_out);
}